// Round 3
// baseline (477.963 us; speedup 1.0000x reference)
//
#include <hip/hip_runtime.h>
#include <hip/hip_bf16.h>

typedef unsigned short u16;
typedef unsigned int u32;
typedef short bf16x8 __attribute__((ext_vector_type(8)));
typedef float f32x4 __attribute__((ext_vector_type(4)));

__device__ inline float bf2f(u16 u) { return __uint_as_float(((u32)u) << 16); }
__device__ inline u16 f2bf(float f) {
    u32 x = __float_as_uint(f);
    return (u16)((x + 0x7FFFu + ((x >> 16) & 1u)) >> 16);  // RNE
}

// ---------------- Kernel 1: Wh_t[b][f][j] = (x @ W)^T (bf16) + fused colsum S ----------------
// Formulated as W^T(f,k) @ x^T(k,j): M=f=128, N=j=128/block, K=128.
__global__ __launch_bounds__(256) void k_gemm1(const float* __restrict__ x,
                                               const float* __restrict__ W,
                                               u16* __restrict__ Wht,
                                               float* __restrict__ S) {
    __shared__ __align__(16) u16 Wt[128][136];  // [f][k], +8 pad
    const int t = threadIdx.x;
    {   // stage W^T into LDS (bf16)
        int k = t >> 1;
        int f0 = (t & 1) * 64;
        const float4* wp = reinterpret_cast<const float4*>(W + k * 128 + f0);
#pragma unroll
        for (int q = 0; q < 16; ++q) {
            float4 v = wp[q];
            int f = f0 + q * 4;
            Wt[f + 0][k] = f2bf(v.x);
            Wt[f + 1][k] = f2bf(v.y);
            Wt[f + 2][k] = f2bf(v.z);
            Wt[f + 3][k] = f2bf(v.w);
        }
    }
    __syncthreads();

    const int w = t >> 6, l = t & 63;
    const int lr = l & 15, lg = l >> 4;
    const int fh = (w & 1) * 64;
    const int jh = (w >> 1) * 64;
    const int j0 = blockIdx.x * 128;  // flat row in x (B*N)

    f32x4 acc[4][4];
#pragma unroll
    for (int m = 0; m < 4; ++m)
#pragma unroll
        for (int n = 0; n < 4; ++n) acc[m][n] = (f32x4){0.f, 0.f, 0.f, 0.f};

#pragma unroll
    for (int ks = 0; ks < 4; ++ks) {
        bf16x8 a[4], bb[4];
#pragma unroll
        for (int m = 0; m < 4; ++m)
            a[m] = *reinterpret_cast<const bf16x8*>(&Wt[fh + m * 16 + lr][ks * 32 + lg * 8]);
#pragma unroll
        for (int n = 0; n < 4; ++n) {
            int j = j0 + jh + n * 16 + lr;
            const float* xp = x + (size_t)j * 128 + ks * 32 + lg * 8;
            float4 v0 = *reinterpret_cast<const float4*>(xp);
            float4 v1 = *reinterpret_cast<const float4*>(xp + 4);
            bf16x8 bv;
            bv[0] = (short)f2bf(v0.x); bv[1] = (short)f2bf(v0.y);
            bv[2] = (short)f2bf(v0.z); bv[3] = (short)f2bf(v0.w);
            bv[4] = (short)f2bf(v1.x); bv[5] = (short)f2bf(v1.y);
            bv[6] = (short)f2bf(v1.z); bv[7] = (short)f2bf(v1.w);
            bb[n] = bv;
        }
#pragma unroll
        for (int m = 0; m < 4; ++m)
#pragma unroll
            for (int n = 0; n < 4; ++n)
                acc[m][n] = __builtin_amdgcn_mfma_f32_16x16x32_bf16(a[m], bb[n], acc[m][n], 0, 0, 0);
    }

    // C layout: col(=j) = lane&15, row(=f) = (lane>>4)*4 + reg
    const int bb_ = blockIdx.x >> 5;          // batch
    const int jj = (blockIdx.x & 31) * 128;   // j within batch
    u16* base = Wht + ((size_t)bb_ << 19);    // 128*4096 per batch
    float* Sb = S + bb_ * 128;
#pragma unroll
    for (int m = 0; m < 4; ++m) {
        int f = fh + m * 16 + lg * 4;
#pragma unroll
        for (int n = 0; n < 4; ++n) {
            int j = jj + jh + n * 16 + lr;
#pragma unroll
            for (int r = 0; r < 4; ++r)
                base[(size_t)(f + r) * 4096 + j] = f2bf(acc[m][n][r]);
        }
        // fused partial column-sum (for empty-row softmax fallback)
#pragma unroll
        for (int r = 0; r < 4; ++r) {
            float sj = 0.f;
#pragma unroll
            for (int n = 0; n < 4; ++n) sj += acc[m][n][r];
            sj += __shfl_xor(sj, 1);
            sj += __shfl_xor(sj, 2);
            sj += __shfl_xor(sj, 4);
            sj += __shfl_xor(sj, 8);
            if (lr == 0) atomicAdd(&Sb[f + r], sj);
        }
    }
}

// ---------------- Kernel 2: out[b][i][f] = (1/cnt_i) * sum_{j: adj>0} Wh[b][j][f] ----------------
// MFMA: M=i (BM=32), N=f (128), K=j (4096, BK=64). A = adj tile (bf16 0/1), B = Wh_t tile.
// grid = 512 (4 batches x 128 i-blocks), 2 independent blocks/CU for latency hiding.
__global__ __launch_bounds__(256) void k_gemm2(const int* __restrict__ adj,
                                               const u16* __restrict__ Wht,
                                               const float* __restrict__ S,
                                               float* __restrict__ out) {
    __shared__ __align__(16) u16 As[2][32][72];
    __shared__ __align__(16) u16 Bs[2][128][72];
    __shared__ int cnt_lds[32];
    __shared__ float inv_lds[32];

    const int t = threadIdx.x;
    // XCD-bijective swizzle (512 % 8 == 0): each XCD gets 64 consecutive
    // i-blocks (half a batch) -> its L2 caches ~1 batch of Wh_t (1 MB).
    const int raw = blockIdx.x;
    const int swz = (raw & 7) * 64 + (raw >> 3);
    const int b = swz >> 7;
    const int i0 = (swz & 127) * 32;
    const int* adjb = adj + ((size_t)b << 24) + (size_t)i0 * 4096;
    const u16* whb = Wht + ((size_t)b << 19);

    // staging assignments
    const int ai = t >> 3;            // A row 0..31 (8 threads/row)
    const int ak = (t & 7) * 8;       // A k-chunk (8 ints = 32 B)
    const int bf = t >> 1;            // B row (f) 0..127
    const int bk = (t & 1) * 32;      // B k-chunk (32 bf16 = 64 B)

    int4 av[2];
    uint4 bv[4];
    int cnt = 0;

    auto issue = [&](int k0) {
        const int4* ap = reinterpret_cast<const int4*>(adjb + (size_t)ai * 4096 + k0 + ak);
        av[0] = ap[0]; av[1] = ap[1];
        const uint4* bp = reinterpret_cast<const uint4*>(whb + (size_t)bf * 4096 + k0 + bk);
        bv[0] = bp[0]; bv[1] = bp[1]; bv[2] = bp[2]; bv[3] = bp[3];
    };
    auto convert_write = [&](int buf) {
        u32 u[4];
#pragma unroll
        for (int q = 0; q < 2; ++q) {
            int4 v = av[q];
            cnt += (v.x > 0) + (v.y > 0) + (v.z > 0) + (v.w > 0);
            u[q * 2 + 0] = ((v.x > 0) ? 0x3F80u : 0u) | (((v.y > 0) ? 0x3F80u : 0u) << 16);
            u[q * 2 + 1] = ((v.z > 0) ? 0x3F80u : 0u) | (((v.w > 0) ? 0x3F80u : 0u) << 16);
        }
        *reinterpret_cast<uint4*>(&As[buf][ai][ak]) = make_uint4(u[0], u[1], u[2], u[3]);
        uint4* bw = reinterpret_cast<uint4*>(&Bs[buf][bf][bk]);
        bw[0] = bv[0]; bw[1] = bv[1]; bw[2] = bv[2]; bw[3] = bv[3];
    };

    const int w = t >> 6, l = t & 63;
    const int lr = l & 15, lg = l >> 4;
    const int ir = w & 1;            // 1 i-frag per wave
    const int fr0 = (w >> 1) * 4;    // 4 f-frags per wave

    f32x4 acc[4];
#pragma unroll
    for (int n = 0; n < 4; ++n) acc[n] = (f32x4){0.f, 0.f, 0.f, 0.f};

    issue(0);
    convert_write(0);
    __syncthreads();

    for (int kt = 0; kt < 64; ++kt) {
        const int cur = kt & 1;
        const bool pre = (kt + 1 < 64);
        if (pre) issue((kt + 1) * 64);  // prefetch next tile into regs

#pragma unroll
        for (int ks = 0; ks < 2; ++ks) {
            bf16x8 a = *reinterpret_cast<const bf16x8*>(&As[cur][ir * 16 + lr][ks * 32 + lg * 8]);
#pragma unroll
            for (int n = 0; n < 4; ++n) {
                bf16x8 bbv = *reinterpret_cast<const bf16x8*>(&Bs[cur][(fr0 + n) * 16 + lr][ks * 32 + lg * 8]);
                acc[n] = __builtin_amdgcn_mfma_f32_16x16x32_bf16(a, bbv, acc[n], 0, 0, 0);
            }
        }

        if (pre) convert_write(cur ^ 1);
        __syncthreads();
    }

    // reduce per-row counts: threads 8i..8i+7 hold partials for row i
    int c = cnt + __shfl_xor(cnt, 1);
    c += __shfl_xor(c, 2);
    c += __shfl_xor(c, 4);
    if ((t & 7) == 0) cnt_lds[ai] = c;
    __syncthreads();
    if (t < 32) {
        int cc = cnt_lds[t];
        inv_lds[t] = (cc > 0) ? (1.0f / (float)cc) : 0.0f;
    }
    __syncthreads();

    float* ob = out + (((size_t)b * 4096) + i0) * 128;
#pragma unroll
    for (int n = 0; n < 4; ++n) {
        int f = (fr0 + n) * 16 + lr;
        float sv = S[b * 128 + f] * (1.0f / 4096.0f);  // empty row: uniform softmax
#pragma unroll
        for (int r = 0; r < 4; ++r) {
            int il = ir * 16 + lg * 4 + r;
            int cc = cnt_lds[il];
            float v = (cc > 0) ? acc[n][r] * inv_lds[il] : sv;
            ob[(size_t)il * 128 + f] = v;
        }
    }
}

extern "C" void kernel_launch(void* const* d_in, const int* in_sizes, int n_in,
                              void* d_out, int out_size, void* d_ws, size_t ws_size,
                              hipStream_t stream) {
    const float* x = (const float*)d_in[0];
    const int* adj = (const int*)d_in[1];
    const float* W = (const float*)d_in[2];
    // d_in[3] (a) is mathematically dead: softmax of a j-constant over the adj
    // support is uniform, so attention = adj / rowsum(adj).
    float* out = (float*)d_out;

    u16* Wht = (u16*)d_ws;                                          // 4*128*4096 bf16 = 4 MB
    float* S = (float*)((char*)d_ws + (size_t)4 * 128 * 4096 * 2);  // 512 f32

    hipMemsetAsync(S, 0, 512 * sizeof(float), stream);
    k_gemm1<<<128, 256, 0, stream>>>(x, W, Wht, S);
    k_gemm2<<<512, 256, 0, stream>>>(adj, Wht, S, out);
}

// Round 5
// 413.526 us; speedup vs baseline: 1.1558x; 1.1558x over previous
//
#include <hip/hip_runtime.h>
#include <hip/hip_bf16.h>

typedef unsigned short u16;
typedef unsigned int u32;
typedef short bf16x8 __attribute__((ext_vector_type(8)));
typedef float f32x4 __attribute__((ext_vector_type(4)));

__device__ inline float bf2f(u16 u) { return __uint_as_float(((u32)u) << 16); }
__device__ inline u16 f2bf(float f) {
    u32 x = __float_as_uint(f);
    return (u16)((x + 0x7FFFu + ((x >> 16) & 1u)) >> 16);  // RNE
}

// ---------------- Kernel 1: Wh_t[b][f][j] = (x @ W)^T (bf16) + fused colsum S ----------------
// (byte-identical to round-3 version: controlled experiment on the ~280us remainder)
__global__ __launch_bounds__(256) void k_gemm1(const float* __restrict__ x,
                                               const float* __restrict__ W,
                                               u16* __restrict__ Wht,
                                               float* __restrict__ S) {
    __shared__ __align__(16) u16 Wt[128][136];
    const int t = threadIdx.x;
    {
        int k = t >> 1;
        int f0 = (t & 1) * 64;
        const float4* wp = reinterpret_cast<const float4*>(W + k * 128 + f0);
#pragma unroll
        for (int q = 0; q < 16; ++q) {
            float4 v = wp[q];
            int f = f0 + q * 4;
            Wt[f + 0][k] = f2bf(v.x);
            Wt[f + 1][k] = f2bf(v.y);
            Wt[f + 2][k] = f2bf(v.z);
            Wt[f + 3][k] = f2bf(v.w);
        }
    }
    __syncthreads();

    const int w = t >> 6, l = t & 63;
    const int lr = l & 15, lg = l >> 4;
    const int fh = (w & 1) * 64;
    const int jh = (w >> 1) * 64;
    const int j0 = blockIdx.x * 128;

    f32x4 acc[4][4];
#pragma unroll
    for (int m = 0; m < 4; ++m)
#pragma unroll
        for (int n = 0; n < 4; ++n) acc[m][n] = (f32x4){0.f, 0.f, 0.f, 0.f};

#pragma unroll
    for (int ks = 0; ks < 4; ++ks) {
        bf16x8 a[4], bb[4];
#pragma unroll
        for (int m = 0; m < 4; ++m)
            a[m] = *reinterpret_cast<const bf16x8*>(&Wt[fh + m * 16 + lr][ks * 32 + lg * 8]);
#pragma unroll
        for (int n = 0; n < 4; ++n) {
            int j = j0 + jh + n * 16 + lr;
            const float* xp = x + (size_t)j * 128 + ks * 32 + lg * 8;
            float4 v0 = *reinterpret_cast<const float4*>(xp);
            float4 v1 = *reinterpret_cast<const float4*>(xp + 4);
            bf16x8 bv;
            bv[0] = (short)f2bf(v0.x); bv[1] = (short)f2bf(v0.y);
            bv[2] = (short)f2bf(v0.z); bv[3] = (short)f2bf(v0.w);
            bv[4] = (short)f2bf(v1.x); bv[5] = (short)f2bf(v1.y);
            bv[6] = (short)f2bf(v1.z); bv[7] = (short)f2bf(v1.w);
            bb[n] = bv;
        }
#pragma unroll
        for (int m = 0; m < 4; ++m)
#pragma unroll
            for (int n = 0; n < 4; ++n)
                acc[m][n] = __builtin_amdgcn_mfma_f32_16x16x32_bf16(a[m], bb[n], acc[m][n], 0, 0, 0);
    }

    const int bb_ = blockIdx.x >> 5;
    const int jj = (blockIdx.x & 31) * 128;
    u16* base = Wht + ((size_t)bb_ << 19);
    float* Sb = S + bb_ * 128;
#pragma unroll
    for (int m = 0; m < 4; ++m) {
        int f = fh + m * 16 + lg * 4;
#pragma unroll
        for (int n = 0; n < 4; ++n) {
            int j = jj + jh + n * 16 + lr;
#pragma unroll
            for (int r = 0; r < 4; ++r)
                base[(size_t)(f + r) * 4096 + j] = f2bf(acc[m][n][r]);
        }
#pragma unroll
        for (int r = 0; r < 4; ++r) {
            float sj = 0.f;
#pragma unroll
            for (int n = 0; n < 4; ++n) sj += acc[m][n][r];
            sj += __shfl_xor(sj, 1);
            sj += __shfl_xor(sj, 2);
            sj += __shfl_xor(sj, 4);
            sj += __shfl_xor(sj, 8);
            if (lr == 0) atomicAdd(&Sb[f + r], sj);
        }
    }
}

// ---------------- Kernel 2: partial[ksp][b][i][f] = sum_{j in half: adj>0} Wh[b][j][f] ----------------
// BM=64, K-split 2 -> grid 512 (2 independent blocks/CU). A (adj) via LDS double-buffer
// with reg prefetch; B (Wh_t, L2-resident panel) gathered global->reg, no LDS, no barrier.
__global__ __launch_bounds__(256) void k_gemm2(const int* __restrict__ adj,
                                               const u16* __restrict__ Wht,
                                               float* __restrict__ part,   // [2][4][4096][128]
                                               int* __restrict__ cnt) {    // [4*4096]
    __shared__ __align__(16) u16 As[2][64][72];  // +8 pad

    const int t = threadIdx.x;
    // XCD-bijective swizzle: XCD x (raw&7) gets swz in [64x, 64x+63] = one (batch, k-half)
    // panel -> 0.5 MB Wh_t panel L2-resident per XCD.
    const int raw = blockIdx.x;
    const int swz = (raw & 7) * 64 + (raw >> 3);
    const int b   = swz >> 7;
    const int ksp = (swz >> 6) & 1;
    const int i0  = (swz & 63) * 64;
    const int koff = ksp * 2048;

    const int* adjb = adj + ((size_t)b << 24) + (size_t)i0 * 4096 + koff;
    const u16* whb  = Wht + ((size_t)b << 19) + koff;

    // A staging: 4 threads per row, 16 ints each
    const int ai = t >> 2;
    const int aq = t & 3;
    const int* aptr = adjb + (size_t)ai * 4096 + aq * 16;

    int4 av[4];
    int cntv = 0;

    auto issueA = [&](int kt) {
        const int4* p = reinterpret_cast<const int4*>(aptr + kt * 64);
        av[0] = p[0]; av[1] = p[1]; av[2] = p[2]; av[3] = p[3];
    };
    auto convertA = [&](int buf) {
        u32 u[8];
#pragma unroll
        for (int q = 0; q < 4; ++q) {
            int4 v = av[q];
            cntv += (v.x > 0) + (v.y > 0) + (v.z > 0) + (v.w > 0);
            u[q * 2 + 0] = ((v.x > 0) ? 0x3F80u : 0u) | (((v.y > 0) ? 0x3F80u : 0u) << 16);
            u[q * 2 + 1] = ((v.z > 0) ? 0x3F80u : 0u) | (((v.w > 0) ? 0x3F80u : 0u) << 16);
        }
        *reinterpret_cast<uint4*>(&As[buf][ai][aq * 16]) = make_uint4(u[0], u[1], u[2], u[3]);
        *reinterpret_cast<uint4*>(&As[buf][ai][aq * 16 + 8]) = make_uint4(u[4], u[5], u[6], u[7]);
    };

    const int w = t >> 6, l = t & 63;
    const int lr = l & 15, lg = l >> 4;
    const int ir0 = (w & 1) * 2;   // 2 i-frags per wave
    const int fr0 = (w >> 1) * 4;  // 4 f-frags per wave

    // B gather base pointers (static-unrolled use only)
    const u16* bptr0 = whb + (size_t)((fr0 + 0) * 16 + lr) * 4096 + lg * 8;
    const u16* bptr1 = whb + (size_t)((fr0 + 1) * 16 + lr) * 4096 + lg * 8;
    const u16* bptr2 = whb + (size_t)((fr0 + 2) * 16 + lr) * 4096 + lg * 8;
    const u16* bptr3 = whb + (size_t)((fr0 + 3) * 16 + lr) * 4096 + lg * 8;

    f32x4 acc[2][4];
#pragma unroll
    for (int m = 0; m < 2; ++m)
#pragma unroll
        for (int n = 0; n < 4; ++n) acc[m][n] = (f32x4){0.f, 0.f, 0.f, 0.f};

    issueA(0);
    convertA(0);
    __syncthreads();

    for (int kt = 0; kt < 32; ++kt) {
        const int cur = kt & 1;
        // B gather first so MFMA's vmcnt wait leaves the A prefetch in flight
        bf16x8 bb0[4], bb1[4];
        bb0[0] = *reinterpret_cast<const bf16x8*>(bptr0 + kt * 64);
        bb0[1] = *reinterpret_cast<const bf16x8*>(bptr1 + kt * 64);
        bb0[2] = *reinterpret_cast<const bf16x8*>(bptr2 + kt * 64);
        bb0[3] = *reinterpret_cast<const bf16x8*>(bptr3 + kt * 64);
        bb1[0] = *reinterpret_cast<const bf16x8*>(bptr0 + kt * 64 + 32);
        bb1[1] = *reinterpret_cast<const bf16x8*>(bptr1 + kt * 64 + 32);
        bb1[2] = *reinterpret_cast<const bf16x8*>(bptr2 + kt * 64 + 32);
        bb1[3] = *reinterpret_cast<const bf16x8*>(bptr3 + kt * 64 + 32);
        if (kt + 1 < 32) issueA(kt + 1);  // reg prefetch of next adj tile

#pragma unroll
        for (int ks = 0; ks < 2; ++ks) {
            bf16x8 a0 = *reinterpret_cast<const bf16x8*>(&As[cur][(ir0 + 0) * 16 + lr][ks * 32 + lg * 8]);
            bf16x8 a1 = *reinterpret_cast<const bf16x8*>(&As[cur][(ir0 + 1) * 16 + lr][ks * 32 + lg * 8]);
#pragma unroll
            for (int n = 0; n < 4; ++n) {
                bf16x8 bv = ks ? bb1[n] : bb0[n];
                acc[0][n] = __builtin_amdgcn_mfma_f32_16x16x32_bf16(a0, bv, acc[0][n], 0, 0, 0);
                acc[1][n] = __builtin_amdgcn_mfma_f32_16x16x32_bf16(a1, bv, acc[1][n], 0, 0, 0);
            }
        }

        if (kt + 1 < 32) convertA(cur ^ 1);
        __syncthreads();
    }

    // per-row count for this K-half: reduce the 4 staging threads of each row
    int c = cntv + __shfl_xor(cntv, 1);
    c += __shfl_xor(c, 2);
    if ((t & 3) == 0) atomicAdd(&cnt[b * 4096 + i0 + ai], c);

    // store partial sums (f32, coalesced over f)
    float* pb = part + ((size_t)ksp << 21) + ((size_t)b * 4096 + i0) * 128;
#pragma unroll
    for (int m = 0; m < 2; ++m) {
#pragma unroll
        for (int n = 0; n < 4; ++n) {
            int f = (fr0 + n) * 16 + lr;
#pragma unroll
            for (int r = 0; r < 4; ++r) {
                int il = (ir0 + m) * 16 + lg * 4 + r;
                pb[(size_t)il * 128 + f] = acc[m][n][r];
            }
        }
    }
}

// ---------------- Kernel 3: out = (part0+part1)/cnt, empty-row fallback ----------------
__global__ __launch_bounds__(256) void k_fin(const float* __restrict__ part,
                                             const int* __restrict__ cnt,
                                             const float* __restrict__ S,
                                             float* __restrict__ out) {
    int e = blockIdx.x * 256 + threadIdx.x;  // 2M elements
    int f = e & 127;
    int row = e >> 7;      // b*4096 + i
    int b = row >> 12;
    int c = cnt[row];
    float p = part[e] + part[e + (1 << 21)];
    float v;
    if (c > 0) v = p / (float)c;
    else       v = S[b * 128 + f] * (1.0f / 4096.0f);  // uniform softmax over all-masked row
    out[e] = v;
}

extern "C" void kernel_launch(void* const* d_in, const int* in_sizes, int n_in,
                              void* d_out, int out_size, void* d_ws, size_t ws_size,
                              hipStream_t stream) {
    const float* x = (const float*)d_in[0];
    const int* adj = (const int*)d_in[1];
    const float* W = (const float*)d_in[2];
    // d_in[3] (a) is mathematically dead: softmax of a j-constant over the adj
    // support is uniform, so attention = adj / rowsum(adj).
    float* out = (float*)d_out;

    char* wsb = (char*)d_ws;
    float* S    = (float*)(wsb);                  // 512 f32 (2 KB)
    int*   cnt  = (int*)(wsb + 4096);             // 16384 i32 (64 KB)
    float* part = (float*)(wsb + (1u << 20));     // 2 x 8 MB f32 partials
    u16*   Wht  = (u16*)(wsb + (1u << 25));       // 4 MB bf16

    hipMemsetAsync(wsb, 0, 4096 + 65536, stream);           // zero S + cnt
    k_gemm1<<<128, 256, 0, stream>>>(x, W, Wht, S);
    k_gemm2<<<512, 256, 0, stream>>>(adj, Wht, part, cnt);
    k_fin<<<8192, 256, 0, stream>>>(part, cnt, S, out);
}